// Round 5
// baseline (619.535 us; speedup 1.0000x reference)
//
#include <hip/hip_runtime.h>
#include <cstdint>
#include <cstddef>

// Problem dims (fixed by reference)
#define BATCH   4096
#define IN_DIM  2048
#define OUT_DIM 2048
#define KDIM    4096   // IN_DIM + OUT_DIM
#define NT      128    // number of 32-wide K tiles

typedef __bf16 bf16x8 __attribute__((ext_vector_type(8)));
typedef float  floatx4 __attribute__((ext_vector_type(4)));

__device__ __forceinline__ unsigned short f2bf(float f) {
  unsigned int u = __float_as_uint(f);
  u += 0x7FFFu + ((u >> 16) & 1u);   // round-to-nearest-even
  return (unsigned short)(u >> 16);
}

__device__ __forceinline__ void async16(const void* g, void* l) {
  __builtin_amdgcn_global_load_lds(
      (const __attribute__((address_space(1))) unsigned int*)g,
      (__attribute__((address_space(3))) unsigned int*)l, 16, 0, 0);
}

// fast tanh via exp2-backed __expf; exact at saturation (exp overflow -> +-1)
__device__ __forceinline__ float tanh_fast(float x) {
  return 1.f - 2.f / (__expf(2.f * x) + 1.f);
}

// ---------------------------------------------------------------------------
// Pack A = [X | H] row-major 4096 x 4096 bf16   (byte-identical to verified)
// ---------------------------------------------------------------------------
__global__ __launch_bounds__(256) void pack_A_kernel(
    const float* __restrict__ X, const float* __restrict__ H,
    unsigned short* __restrict__ A) {
  int idx = blockIdx.x * 256 + threadIdx.x;   // 0 .. 4194303
  int e = idx << 2;                           // element index (groups of 4)
  int m = e >> 12;                            // /4096
  int k = e & 4095;
  const float* src = (k < IN_DIM) ? (X + (size_t)m * IN_DIM + k)
                                  : (H + (size_t)m * OUT_DIM + (k - IN_DIM));
  float4 v = *(const float4*)src;
  ushort4 o;
  o.x = f2bf(v.x); o.y = f2bf(v.y); o.z = f2bf(v.z); o.w = f2bf(v.w);
  *(ushort4*)(A + e) = o;
}

// ---------------------------------------------------------------------------
// Pack Bt: 8192(n) x 4096(k) bf16, n = gate*2048 + c, gates ordered f,i,o,g.
// (byte-identical to verified baseline)
// ---------------------------------------------------------------------------
__global__ __launch_bounds__(256) void pack_B_kernel(
    const float* __restrict__ Wxf, const float* __restrict__ Wxi,
    const float* __restrict__ Wxo, const float* __restrict__ Wxg,
    const float* __restrict__ Whf, const float* __restrict__ Whi,
    const float* __restrict__ Who, const float* __restrict__ Whg,
    unsigned short* __restrict__ Bt) {
  __shared__ float tile[64][33];
  int bx = blockIdx.x;             // 0 .. 16383
  int kT = bx & 63;                // 0..63
  int nT = bx >> 6;                // 0..255
  int k0 = kT * 64, n0 = nT * 32;
  int g = n0 >> 11;                // gate; tiles never straddle (2048%32==0)
  int c0 = n0 & 2047;
  const float* W;
  int kk0;
  if (k0 < IN_DIM) {               // 2048 % 64 == 0: no straddle in k either
    kk0 = k0;
    W = (g == 0) ? Wxf : (g == 1) ? Wxi : (g == 2) ? Wxo : Wxg;
  } else {
    kk0 = k0 - IN_DIM;
    W = (g == 0) ? Whf : (g == 1) ? Whi : (g == 2) ? Who : Whg;
  }
  int t = threadIdx.x;
#pragma unroll
  for (int i = 0; i < 2; ++i) {
    int idx = i * 256 + t;
    int lk = idx >> 3, lc = (idx & 7) * 4;
    float4 v = *(const float4*)(W + (size_t)(kk0 + lk) * 2048 + c0 + lc);
    tile[lk][lc]     = v.x;
    tile[lk][lc + 1] = v.y;
    tile[lk][lc + 2] = v.z;
    tile[lk][lc + 3] = v.w;
  }
  __syncthreads();
  int ln = t >> 3, k8 = (t & 7) * 8;
  unsigned int p[4];
#pragma unroll
  for (int j = 0; j < 4; ++j) {
    unsigned int lo = f2bf(tile[k8 + 2 * j][ln]);
    unsigned int hi = f2bf(tile[k8 + 2 * j + 1][ln]);
    p[j] = lo | (hi << 16);
  }
  uint4 o = make_uint4(p[0], p[1], p[2], p[3]);
  *(uint4*)(Bt + (size_t)(n0 + ln) * KDIM + k0 + k8) = o;
}

// ---------------------------------------------------------------------------
// Fused LSTM GEMM — counted-vmcnt pipeline, 2 blocks/CU for TLP stall cover.
//   256 thr (4 waves, 2M x 2N), tile 128(M) x [64 cols x 4 gates], BK=32.
//   Wave output: 64(m) x [32 cols x 4 gates]; acc[4 g][2 nf2][4 mt] = 128
//   regs (AGPR). Per tile per wave: 12 ds_read_b128 -> 32 MFMA; A frags
//   reused across both phases (read once).
//   LDS: 2-slot ring, slot = A[128x32] 8KB + B[256x32] 16KB = 24 KB ->
//   48 KB static; 2 blocks co-resident per CU (96 KB LDS, 8 waves x ~244
//   regs = 488/512 per SIMD). Independent barrier domains: when one block
//   waits on vmcnt, the sibling's waves feed the MFMA pipe.
//   Load groups per thread per tile: G1 = {a1,a2,b0,b1} (4 loads: all A +
//   B gates 0,1), G2 = {b2,b3} (2 loads: B gates 2,3).
//   Issue points: G2(t+1) in phase A of t -> slot (t+1)&1 gates23 region
//   (readers: tile t-1 phase B, drained before the phase-A(t) barrier);
//   G1(t+2) in phase B of t -> slot t&1 A+gates01 regions (readers: tile t
//   phase A, drained before the phase-B(t) barrier; phase B reuses af from
//   registers, never re-reads the A region).
//   Waits (issue order G1(t),G2(t),G1(t+1),G2(t+1),...):
//     phase A(t): newer-than-G1(t) = G2(t)+G1(t+1) = 6 -> s_waitcnt vmcnt(6)
//     phase B(t): newer-than-G2(t) = G1(t+1)+G2(t+1) = 6 -> vmcnt(6)
//     NEVER 0 in the main loop; last tile peeled with vmcnt(2)/vmcnt(0).
//   Swizzle: linear LDS dest; stage source chunk = (t&3)^((rowT>>1)&3);
//   read chunk = fk^((fr>>1)&3); all fragment row bases are multiples of 16
//   so the involutions agree (verified pattern, 0 conflicts measured).
// ---------------------------------------------------------------------------
template <bool LAST, bool IG1, bool IG2>
__device__ __forceinline__ void do_tile(
    const char* sl, char* snA, char* snB,
    const char* aG1, const char* aG2, const char* bGp0, const char* bGp1,
    const char* bGp2, const char* bGp3,
    unsigned kbG1, unsigned kbG2, int t16,
    int aOff, int bOff, floatx4 (&acc)[4][2][4]) {
  bf16x8 af[4], bfr[2][2];
  // ================= phase A: gates 0,1 =================
  if (LAST) asm volatile("s_waitcnt vmcnt(2)" ::: "memory");
  else      asm volatile("s_waitcnt vmcnt(6)" ::: "memory");
  asm volatile("s_barrier" ::: "memory");
#pragma unroll
  for (int mt = 0; mt < 4; ++mt)
    af[mt] = *(const bf16x8*)(sl + aOff + mt * 1024);
#pragma unroll
  for (int g = 0; g < 2; ++g)
#pragma unroll
    for (int nf2 = 0; nf2 < 2; ++nf2)
      bfr[g][nf2] = *(const bf16x8*)(sl + bOff + g * 4096 + nf2 * 1024);
  if (IG2) {
    async16(bGp2 + kbG2, snB + 16384 + t16);
    async16(bGp3 + kbG2, snB + 20480 + t16);
  }
  __builtin_amdgcn_s_setprio(1);
#pragma unroll
  for (int g = 0; g < 2; ++g)
#pragma unroll
    for (int nf2 = 0; nf2 < 2; ++nf2)
#pragma unroll
      for (int mt = 0; mt < 4; ++mt)
        acc[g][nf2][mt] = __builtin_amdgcn_mfma_f32_16x16x32_bf16(
            af[mt], bfr[g][nf2], acc[g][nf2][mt], 0, 0, 0);
  __builtin_amdgcn_s_setprio(0);
  // ================= phase B: gates 2,3 (af reused from regs) ============
  if (LAST) asm volatile("s_waitcnt vmcnt(0)" ::: "memory");
  else      asm volatile("s_waitcnt vmcnt(6)" ::: "memory");
  asm volatile("s_barrier" ::: "memory");
#pragma unroll
  for (int g = 0; g < 2; ++g)
#pragma unroll
    for (int nf2 = 0; nf2 < 2; ++nf2)
      bfr[g][nf2] = *(const bf16x8*)(sl + bOff + (g + 2) * 4096 + nf2 * 1024);
  if (IG1) {
    async16(aG1 + kbG1, snA + t16);
    async16(aG2 + kbG1, snA + 4096 + t16);
    async16(bGp0 + kbG1, snA + 8192 + t16);
    async16(bGp1 + kbG1, snA + 12288 + t16);
  }
  __builtin_amdgcn_s_setprio(1);
#pragma unroll
  for (int g = 0; g < 2; ++g)
#pragma unroll
    for (int nf2 = 0; nf2 < 2; ++nf2)
#pragma unroll
      for (int mt = 0; mt < 4; ++mt)
        acc[g + 2][nf2][mt] = __builtin_amdgcn_mfma_f32_16x16x32_bf16(
            af[mt], bfr[g][nf2], acc[g + 2][nf2][mt], 0, 0, 0);
  __builtin_amdgcn_s_setprio(0);
}

__global__ __launch_bounds__(256, 2) void lstm_gemm_fused(
    const unsigned short* __restrict__ A,    // 4096 x 4096 bf16
    const unsigned short* __restrict__ Bt,   // 8192 x 4096 bf16
    const float* __restrict__ Cin,           // 4096 x 2048
    const float* __restrict__ bF, const float* __restrict__ bI,
    const float* __restrict__ bO, const float* __restrict__ bG,
    float* __restrict__ outC, float* __restrict__ outY) {
  __shared__ __align__(16) char smem[49152];   // 2 slots x 24 KB, static

  const int t = threadIdx.x;                 // 0..255
  const int lane = t & 63;
  const int w = t >> 6;                      // wave 0..3
  const int wm = w >> 1;                     // m-half 0..1 (64 rows each)
  const int wn = w & 1;                      // col-half 0..1 (32 cols)

  // bijective XCD swizzle (1024 % 8 == 0): XCD x gets 128 contiguous wgids
  // = 4 full by-rows -> per-XCD A panels (4 MB) L2-resident.
  const int orig = blockIdx.x;
  const int wgid = (orig & 7) * 128 + (orig >> 3);
  const int bx = wgid & 31;                  // n tile: 64 cols per gate
  const int by = wgid >> 5;                  // m tile: 128 rows (0..31)
  const int mBase = by * 128;

  floatx4 acc[4][2][4];                      // [gate][nf2][mt]
#pragma unroll
  for (int g = 0; g < 4; ++g)
#pragma unroll
    for (int nf2 = 0; nf2 < 2; ++nf2)
#pragma unroll
      for (int mt = 0; mt < 4; ++mt)
        acc[g][nf2][mt] = (floatx4){0.f, 0.f, 0.f, 0.f};

  // ---- staging: thread t owns LDS L-row rowT = t>>2 (0..63), chunk t&3;
  // global source chunk pre-swizzled: (t&3) ^ ((t>>3)&3) = (t&3)^((rowT>>1)&3).
  const int rowT = t >> 2;                   // 0..63
  const int cswz = ((t & 3) ^ ((t >> 3) & 3)) * 16;     // byte offset in row
  const char* aG1 = (const char*)A + ((size_t)(mBase + rowT) * KDIM) * 2 + cswz;
  const char* aG2 = aG1 + (size_t)64 * KDIM * 2;        // rows 64..127
  const char* bGp0 = (const char*)Bt +
      ((size_t)(0 * 2048 + bx * 64 + rowT) * KDIM) * 2 + cswz;
  const char* bGp1 = bGp0 + (size_t)2048 * KDIM * 2;    // gate 1
  const char* bGp2 = bGp0 + (size_t)4096 * KDIM * 2;    // gate 2
  const char* bGp3 = bGp0 + (size_t)6144 * KDIM * 2;    // gate 3
  const int t16 = t * 16;

  // ---- fragment read offsets (L-row*64B + swizzled chunk*16B)
  const int fr = lane & 15;
  const int fkxB = (((lane >> 4) ^ ((fr >> 1) & 3))) * 16;
  // A: L-row = wm*64 + mt*16 + fr
  const int aOff = (wm * 64 + fr) * 64 + fkxB;          // + mt*1024
  // B: L-row = g*64 + wn*32 + nf2*16 + fr, region base 8192
  const int bOff = 8192 + (wn * 32 + fr) * 64 + fkxB;   // + g*4096 + nf2*1024

  // ---- prologue: issue G1(0) [4], G2(0) [2], G1(1) [4]  (10 loads)
  async16(aG1,       smem + t16);
  async16(aG2,       smem + 4096 + t16);
  async16(bGp0,      smem + 8192 + t16);
  async16(bGp1,      smem + 12288 + t16);
  async16(bGp2,      smem + 16384 + t16);
  async16(bGp3,      smem + 20480 + t16);
  async16(aG1 + 64,  smem + 24576 + t16);
  async16(aG2 + 64,  smem + 24576 + 4096 + t16);
  async16(bGp0 + 64, smem + 24576 + 8192 + t16);
  async16(bGp1 + 64, smem + 24576 + 12288 + t16);

  // ---- main loop: tiles 0..NT-3 steady; peel NT-2 (no G1) and NT-1
  for (int tt = 0; tt < NT - 2; ++tt) {
    const char* sl = smem + (tt & 1) * 24576;
    char* snA = const_cast<char*>(sl);               // G1(t+2): current slot
    char* snB = smem + ((tt + 1) & 1) * 24576;       // G2(t+1): next slot
    do_tile<false, true, true>(sl, snA, snB, aG1, aG2, bGp0, bGp1, bGp2, bGp3,
                               (unsigned)(tt + 2) * 64, (unsigned)(tt + 1) * 64,
                               t16, aOff, bOff, acc);
  }
  {
    const int tt = NT - 2;
    const char* sl = smem + (tt & 1) * 24576;
    char* snA = const_cast<char*>(sl);
    char* snB = smem + ((tt + 1) & 1) * 24576;
    do_tile<false, false, true>(sl, snA, snB, aG1, aG2, bGp0, bGp1, bGp2, bGp3,
                                0, (unsigned)(tt + 1) * 64,
                                t16, aOff, bOff, acc);
  }
  {
    const int tt = NT - 1;
    const char* sl = smem + (tt & 1) * 24576;
    char* snA = const_cast<char*>(sl);
    char* snB = smem + ((tt + 1) & 1) * 24576;
    do_tile<true, false, false>(sl, snA, snB, aG1, aG2, bGp0, bGp1, bGp2, bGp3,
                                0, 0, t16, aOff, bOff, acc);
  }

  // ---- fused LSTM epilogue. C/D: col=lane&15, row=(lane>>4)*4+reg.
  // acc[g] is gate g (B LDS region) at cols bx*64 + wn*32 + nf2*16 + fr.
  const int col0 = bx * 64 + wn * 32 + fr;   // nf2=0 column
  const int rb = mBase + wm * 64 + ((lane >> 4) << 2);
#pragma unroll
  for (int nf2 = 0; nf2 < 2; ++nf2) {
    const int col = col0 + nf2 * 16;
    const float bfv = bF[col], biv = bI[col], bov = bO[col], bgv = bG[col];
#pragma unroll
    for (int mt = 0; mt < 4; ++mt) {
#pragma unroll
      for (int r = 0; r < 4; ++r) {
        const int row = rb + mt * 16 + r;
        const size_t off = (size_t)row * OUT_DIM + col;
        float pf = acc[0][nf2][mt][r] + bfv;
        float pi = acc[1][nf2][mt][r] + biv;
        float po = acc[2][nf2][mt][r] + bov;
        float pg = acc[3][nf2][mt][r] + bgv;
        float F = 1.f / (1.f + __expf(-pf));
        float I = 1.f / (1.f + __expf(-pi));
        float O = 1.f / (1.f + __expf(-po));
        float G = tanh_fast(pg);
        float c_new = G * I + F * Cin[off];
        outC[off] = c_new;
        outY[off] = O * tanh_fast(c_new);
      }
    }
  }
}

// ---------------------------------------------------------------------------
extern "C" void kernel_launch(void* const* d_in, const int* in_sizes, int n_in,
                              void* d_out, int out_size, void* d_ws, size_t ws_size,
                              hipStream_t stream) {
  // setup_inputs order: X C H W_xf W_xg W_xi W_xo W_hf W_hg W_hi W_ho b_f b_g b_i b_o
  const float* X   = (const float*)d_in[0];
  const float* C   = (const float*)d_in[1];
  const float* H   = (const float*)d_in[2];
  const float* Wxf = (const float*)d_in[3];
  const float* Wxg = (const float*)d_in[4];
  const float* Wxi = (const float*)d_in[5];
  const float* Wxo = (const float*)d_in[6];
  const float* Whf = (const float*)d_in[7];
  const float* Whg = (const float*)d_in[8];
  const float* Whi = (const float*)d_in[9];
  const float* Who = (const float*)d_in[10];
  const float* bf_ = (const float*)d_in[11];
  const float* bg_ = (const float*)d_in[12];
  const float* bi_ = (const float*)d_in[13];
  const float* bo_ = (const float*)d_in[14];

  float* outC = (float*)d_out;
  float* outY = (float*)d_out + (size_t)BATCH * OUT_DIM;

  // workspace layout: A bf16 (32 MB) | Bt bf16 (64 MB)  => 96 MB needed
  unsigned short* A  = (unsigned short*)d_ws;
  unsigned short* Bt = A + (size_t)BATCH * KDIM;

  // 1) pack A = [X|H] -> bf16
  pack_A_kernel<<<(BATCH * KDIM / 4) / 256, 256, 0, stream>>>(X, H, A);
  // 2) pack Bt (transpose + gate concat + bf16)
  pack_B_kernel<<<64 * 256, 256, 0, stream>>>(Wxf, Wxi, Wxo, Wxg,
                                              Whf, Whi, Who, Whg, Bt);
  // 3) fused GEMM + LSTM epilogue: 1024 blocks (32 bx x 32 by) x 256 thr
  lstm_gemm_fused<<<dim3(1024), dim3(256), 0, stream>>>(
      A, Bt, C, bf_, bi_, bo_, bg_, outC, outY);
}

// Round 7
// 496.148 us; speedup vs baseline: 1.2487x; 1.2487x over previous
//
#include <hip/hip_runtime.h>
#include <cstdint>
#include <cstddef>

// Problem dims (fixed by reference)
#define BATCH   4096
#define IN_DIM  2048
#define OUT_DIM 2048
#define KDIM    4096   // IN_DIM + OUT_DIM
#define NT      128    // number of 32-wide K tiles

typedef __bf16 bf16x8 __attribute__((ext_vector_type(8)));
typedef float  floatx4 __attribute__((ext_vector_type(4)));

__device__ __forceinline__ unsigned short f2bf(float f) {
  unsigned int u = __float_as_uint(f);
  u += 0x7FFFu + ((u >> 16) & 1u);   // round-to-nearest-even
  return (unsigned short)(u >> 16);
}

__device__ __forceinline__ void async16(const void* g, void* l) {
  __builtin_amdgcn_global_load_lds(
      (const __attribute__((address_space(1))) unsigned int*)g,
      (__attribute__((address_space(3))) unsigned int*)l, 16, 0, 0);
}

template <int N>
__device__ __forceinline__ void waitv() {
  if constexpr (N == 0)      asm volatile("s_waitcnt vmcnt(0)" ::: "memory");
  else if constexpr (N == 1) asm volatile("s_waitcnt vmcnt(1)" ::: "memory");
  else if constexpr (N == 4) asm volatile("s_waitcnt vmcnt(4)" ::: "memory");
}

// fast tanh via exp2-backed __expf; exact at saturation (exp overflow -> +-1)
__device__ __forceinline__ float tanh_fast(float x) {
  return 1.f - 2.f / (__expf(2.f * x) + 1.f);
}

// ---------------------------------------------------------------------------
// Pack A = [X | H] row-major 4096 x 4096 bf16   (byte-identical to verified)
// ---------------------------------------------------------------------------
__global__ __launch_bounds__(256) void pack_A_kernel(
    const float* __restrict__ X, const float* __restrict__ H,
    unsigned short* __restrict__ A) {
  int idx = blockIdx.x * 256 + threadIdx.x;   // 0 .. 4194303
  int e = idx << 2;                           // element index (groups of 4)
  int m = e >> 12;                            // /4096
  int k = e & 4095;
  const float* src = (k < IN_DIM) ? (X + (size_t)m * IN_DIM + k)
                                  : (H + (size_t)m * OUT_DIM + (k - IN_DIM));
  float4 v = *(const float4*)src;
  ushort4 o;
  o.x = f2bf(v.x); o.y = f2bf(v.y); o.z = f2bf(v.z); o.w = f2bf(v.w);
  *(ushort4*)(A + e) = o;
}

// ---------------------------------------------------------------------------
// Pack Bt: 8192(n) x 4096(k) bf16, n = gate*2048 + c, gates ordered f,i,o,g.
// Bt[n][k] = k<2048 ? W_x(g)[k][c] : W_h(g)[k-2048][c]   (a transpose)
// WIDENED tiles: 64(k) x 128(c) per block (4096 blocks).
//   reads: 512 B contiguous per W row (32 float4); writes: each thread owns
//   64 B contiguous of one Bt row. LDS tile padded [64][129].
// ---------------------------------------------------------------------------
__global__ __launch_bounds__(256) void pack_B_kernel(
    const float* __restrict__ Wxf, const float* __restrict__ Wxi,
    const float* __restrict__ Wxo, const float* __restrict__ Wxg,
    const float* __restrict__ Whf, const float* __restrict__ Whi,
    const float* __restrict__ Who, const float* __restrict__ Whg,
    unsigned short* __restrict__ Bt) {
  __shared__ float tile[64][129];
  int bid = blockIdx.x;            // 0 .. 4095
  int kT = bid & 63;               // 0..63
  int nT = bid >> 6;               // 0..63
  int k0 = kT * 64;
  int g  = nT >> 4;                // gate 0..3 (f,i,o,g)
  int c0 = (nT & 15) * 128;        // col base within gate
  const float* W;
  int kk0;
  if (k0 < IN_DIM) {               // 2048 % 64 == 0: no straddle in k
    kk0 = k0;
    W = (g == 0) ? Wxf : (g == 1) ? Wxi : (g == 2) ? Wxo : Wxg;
  } else {
    kk0 = k0 - IN_DIM;
    W = (g == 0) ? Whf : (g == 1) ? Whi : (g == 2) ? Who : Whg;
  }
  int t = threadIdx.x;
#pragma unroll
  for (int i = 0; i < 8; ++i) {
    int idx = i * 256 + t;         // 0..2047
    int lk = idx >> 5;             // row 0..63
    int lc = (idx & 31) * 4;       // col 0..124
    float4 v = *(const float4*)(W + (size_t)(kk0 + lk) * 2048 + c0 + lc);
    tile[lk][lc]     = v.x;
    tile[lk][lc + 1] = v.y;
    tile[lk][lc + 2] = v.z;
    tile[lk][lc + 3] = v.w;
  }
  __syncthreads();
  int ln = t >> 1;                 // Bt row (c offset) 0..127
  int half = t & 1;                // which 64 B half of the 128 B row
  const size_t nrow = (size_t)(g * 2048 + c0 + ln);
  uint4* dst = (uint4*)(Bt + nrow * KDIM + k0) + half * 4;
#pragma unroll
  for (int jj = 0; jj < 4; ++jj) {
    int j = half * 4 + jj;         // uint4 index within row: k = j*8..j*8+7
    unsigned int p[4];
#pragma unroll
    for (int q = 0; q < 4; ++q) {
      unsigned int lo = f2bf(tile[j * 8 + 2 * q][ln]);
      unsigned int hi = f2bf(tile[j * 8 + 2 * q + 1][ln]);
      p[q] = lo | (hi << 16);
    }
    dst[jj] = make_uint4(p[0], p[1], p[2], p[3]);
  }
}

// ---------------------------------------------------------------------------
// Fused LSTM GEMM — verified round-4 structure (64 KB static, 2-slot ring,
// counted vmcnt, never 0 in loop) + RECTANGULAR XCD swizzle.
//   512 thr (8 waves, 2M x 4N), tile 256(M) x [64 cols x 4 gates], BK=32.
//   Slot (32 KB): [0,8K) A-phaseA (phys m {0-63,128-191}), [8K,16K) A-phaseB
//   (phys {64-127,192-255}), [16K,24K) B gates 0,1, [24K,32K) B gates 2,3.
//   Loads/thread/tile: G1={a1,b1,b2} (phase-A A rows + all B), G2={a2}.
//   Issue: G2(t+1) in phase A(t) (region readers = tile t-1 phase B, drained
//   before the phase-A(t) barrier); G1(t+2) in phase B(t) (region readers =
//   tile t phase A, drained before the phase-B(t) barrier).
//   Waits: entering A(t): vmcnt(4) [outstanding G2(t)+G1(t+1)=4, retires
//   G1(t)]; entering B(t): vmcnt(4) [outstanding G1(t+1)+G2(t+1), retires
//   G2(t)]. NEVER 0 in the loop; last tile peeled vmcnt(1)/vmcnt(0).
//   Swizzle: linear LDS dest; stage source chunk = (t&3)^((rowT>>1)&3);
//   read chunk = fk^((fr>>1)&3); fragment row bases are multiples of 16 so
//   involutions agree (verified, 0 bank conflicts).
//   XCD tiling (NEW): XCD x = orig&7 owns an 8bx x 8by rectangle; the 32
//   concurrent blocks (1 block/CU) form an 8x4 sub-rect -> every Bt k-slice
//   shared by 4 blocks, every A k-slice by 8; moving k-window ~192 KB << 4MB
//   L2 -> staging latency ~L2, which the 2-phase prefetch distance covers.
// ---------------------------------------------------------------------------
template <bool LAST, bool IG1, bool IG2>
__device__ __forceinline__ void do_tile(
    const char* sl, char* sn,
    const char* aG_1, const char* aG_2, const char* bG_1, const char* bG_2,
    unsigned kbG1, unsigned kbG2, int t16,
    int aOffA, int bOff, floatx4 (&acc)[4][8]) {
  bf16x8 af[4], bfr[4];
  // ================= phase A =================
  if (LAST) waitv<1>(); else waitv<4>();
  asm volatile("s_barrier" ::: "memory");
#pragma unroll
  for (int mt = 0; mt < 4; ++mt)
    af[mt] = *(const bf16x8*)(sl + aOffA + mt * 1024);
#pragma unroll
  for (int nf = 0; nf < 4; ++nf)
    bfr[nf] = *(const bf16x8*)(sl + bOff + nf * 4096);
  if (IG2) async16(aG_2 + kbG2, sn + 8192 + t16);
  __builtin_amdgcn_s_setprio(1);
#pragma unroll
  for (int nf = 0; nf < 4; ++nf)
#pragma unroll
    for (int mt = 0; mt < 4; ++mt)
      acc[nf][mt] = __builtin_amdgcn_mfma_f32_16x16x32_bf16(
          af[mt], bfr[nf], acc[nf][mt], 0, 0, 0);
  __builtin_amdgcn_s_setprio(0);
  // ================= phase B =================
  if (LAST) waitv<0>(); else waitv<4>();
  asm volatile("s_barrier" ::: "memory");
#pragma unroll
  for (int mt = 0; mt < 4; ++mt)
    af[mt] = *(const bf16x8*)(sl + aOffA + 8192 + mt * 1024);
  if (IG1) {
    char* sc = const_cast<char*>(sl);     // G1(t+2) targets the CURRENT slot
    async16(aG_1 + kbG1, sc + t16);
    async16(bG_1 + kbG1, sc + 16384 + t16);
    async16(bG_2 + kbG1, sc + 24576 + t16);
  }
  __builtin_amdgcn_s_setprio(1);
#pragma unroll
  for (int nf = 0; nf < 4; ++nf)
#pragma unroll
    for (int mt = 0; mt < 4; ++mt)
      acc[nf][mt + 4] = __builtin_amdgcn_mfma_f32_16x16x32_bf16(
          af[mt], bfr[nf], acc[nf][mt + 4], 0, 0, 0);
  __builtin_amdgcn_s_setprio(0);
}

__global__ __launch_bounds__(512, 2) void lstm_gemm_fused(
    const unsigned short* __restrict__ A,    // 4096 x 4096 bf16
    const unsigned short* __restrict__ Bt,   // 8192 x 4096 bf16
    const float* __restrict__ Cin,           // 4096 x 2048
    const float* __restrict__ bF, const float* __restrict__ bI,
    const float* __restrict__ bO, const float* __restrict__ bG,
    float* __restrict__ outC, float* __restrict__ outY) {
  __shared__ __align__(16) char smem[65536];   // 2 slots x 32 KB, static

  const int t = threadIdx.x;                 // 0..511
  const int lane = t & 63;
  const int w = t >> 6;                      // wave 0..7
  const int wm = w >> 2;                     // m-half 0..1 (128 rows each)
  const int wn = w & 3;                      // n-quarter (16 cols x 4 gates)

  // ---- rectangular XCD tiling: XCD (orig&7) owns 8bx x 8by; concurrent
  // 32 blocks form an 8x4 sub-rect (u = 0..31 first generation).
  const int orig = blockIdx.x;
  const int x = orig & 7;
  const int u = orig >> 3;                   // 0..63
  const int bx = (x & 3) * 8 + (u & 7);      // 0..31
  const int by = (x >> 2) * 8 + (u >> 3);    // 0..15
  const int mBase = by * 256;

  floatx4 acc[4][8];
#pragma unroll
  for (int g = 0; g < 4; ++g)
#pragma unroll
    for (int mt = 0; mt < 8; ++mt) acc[g][mt] = (floatx4){0.f, 0.f, 0.f, 0.f};

  const int rowT = t >> 2;                   // 0..127
  const int cswz = ((t & 3) ^ ((t >> 3) & 3)) * 16;
  const int physA = rowT + (rowT & 64);      // {0-63,128-191}
  const char* aG_1 = (const char*)A + ((size_t)(mBase + physA) * KDIM) * 2 + cswz;
  const char* aG_2 = aG_1 + (size_t)64 * KDIM * 2;      // {64-127,192-255}
  const int bRow = (rowT >> 6) * 2048 + bx * 64 + (rowT & 63);
  const char* bG_1 = (const char*)Bt + ((size_t)bRow * KDIM) * 2 + cswz;
  const char* bG_2 = bG_1 + (size_t)4096 * KDIM * 2;    // gates 2,3
  const int t16 = t * 16;

  const int fr = lane & 15;
  const int fkxB = (((lane >> 4) ^ ((fr >> 1) & 3))) * 16;
  const int aOffA = (wm * 64 + fr) * 64 + fkxB;         // + mt*1024; +8192 ph.B
  const int bOff = 16384 + (wn * 16 + fr) * 64 + fkxB;  // + nf*4096

  // ---- prologue: G1(0) [3], G2(0) [1], G1(1) [3]  (7 loads)
  async16(aG_1,      smem + t16);
  async16(bG_1,      smem + 16384 + t16);
  async16(bG_2,      smem + 24576 + t16);
  async16(aG_2,      smem + 8192 + t16);
  async16(aG_1 + 64, smem + 32768 + t16);
  async16(bG_1 + 64, smem + 32768 + 16384 + t16);
  async16(bG_2 + 64, smem + 32768 + 24576 + t16);

  // ---- main loop: tiles 0..NT-3 steady; peel NT-2 (no G1) and NT-1
  for (int tt = 0; tt < NT - 2; ++tt) {
    const char* sl = smem + (tt & 1) * 32768;
    char* sn = smem + ((tt + 1) & 1) * 32768;
    do_tile<false, true, true>(sl, sn, aG_1, aG_2, bG_1, bG_2,
                               (unsigned)(tt + 2) * 64,
                               (unsigned)(tt + 1) * 64,
                               t16, aOffA, bOff, acc);
  }
  {
    const int tt = NT - 2;
    const char* sl = smem + (tt & 1) * 32768;
    char* sn = smem + ((tt + 1) & 1) * 32768;
    do_tile<false, false, true>(sl, sn, aG_1, aG_2, bG_1, bG_2,
                                0, (unsigned)(tt + 1) * 64,
                                t16, aOffA, bOff, acc);
  }
  {
    const int tt = NT - 1;
    const char* sl = smem + (tt & 1) * 32768;
    char* sn = smem + ((tt + 1) & 1) * 32768;
    do_tile<true, false, false>(sl, sn, aG_1, aG_2, bG_1, bG_2,
                                0, 0, t16, aOffA, bOff, acc);
  }

  // ---- fused LSTM epilogue. C/D: col=lane&15, row=(lane>>4)*4+reg.
  const int col = bx * 64 + wn * 16 + fr;    // 0..2047
  const float bfv = bF[col], biv = bI[col], bov = bO[col], bgv = bG[col];
  const int rb = mBase + wm * 128 + ((lane >> 4) << 2);
#pragma unroll
  for (int mt = 0; mt < 8; ++mt) {
#pragma unroll
    for (int r = 0; r < 4; ++r) {
      const int row = rb + mt * 16 + r;
      const size_t off = (size_t)row * OUT_DIM + col;
      float pf = acc[0][mt][r] + bfv;
      float pi = acc[1][mt][r] + biv;
      float po = acc[2][mt][r] + bov;
      float pg = acc[3][mt][r] + bgv;
      float F = 1.f / (1.f + __expf(-pf));
      float I = 1.f / (1.f + __expf(-pi));
      float O = 1.f / (1.f + __expf(-po));
      float G = tanh_fast(pg);
      float c_new = G * I + F * Cin[off];
      outC[off] = c_new;
      outY[off] = O * tanh_fast(c_new);
    }
  }
}

// ---------------------------------------------------------------------------
extern "C" void kernel_launch(void* const* d_in, const int* in_sizes, int n_in,
                              void* d_out, int out_size, void* d_ws, size_t ws_size,
                              hipStream_t stream) {
  // setup_inputs order: X C H W_xf W_xg W_xi W_xo W_hf W_hg W_hi W_ho b_f b_g b_i b_o
  const float* X   = (const float*)d_in[0];
  const float* C   = (const float*)d_in[1];
  const float* H   = (const float*)d_in[2];
  const float* Wxf = (const float*)d_in[3];
  const float* Wxg = (const float*)d_in[4];
  const float* Wxi = (const float*)d_in[5];
  const float* Wxo = (const float*)d_in[6];
  const float* Whf = (const float*)d_in[7];
  const float* Whg = (const float*)d_in[8];
  const float* Whi = (const float*)d_in[9];
  const float* Who = (const float*)d_in[10];
  const float* bf_ = (const float*)d_in[11];
  const float* bg_ = (const float*)d_in[12];
  const float* bi_ = (const float*)d_in[13];
  const float* bo_ = (const float*)d_in[14];

  float* outC = (float*)d_out;
  float* outY = (float*)d_out + (size_t)BATCH * OUT_DIM;

  // workspace layout: A bf16 (32 MB) | Bt bf16 (64 MB)  => 96 MB needed
  unsigned short* A  = (unsigned short*)d_ws;
  unsigned short* Bt = A + (size_t)BATCH * KDIM;

  // 1) pack A = [X|H] -> bf16
  pack_A_kernel<<<(BATCH * KDIM / 4) / 256, 256, 0, stream>>>(X, H, A);
  // 2) pack Bt (transpose + gate concat + bf16), widened 64k x 128c tiles
  pack_B_kernel<<<4096, 256, 0, stream>>>(Wxf, Wxi, Wxo, Wxg,
                                          Whf, Whi, Who, Whg, Bt);
  // 3) fused GEMM + LSTM epilogue: 512 blocks x 512 thr, 64 KB static LDS
  lstm_gemm_fused<<<dim3(512), dim3(512), 0, stream>>>(
      A, Bt, C, bf_, bi_, bo_, bg_, outC, outY);
}